// Round 12
// baseline (868.351 us; speedup 1.0000x reference)
//
#include <hip/hip_runtime.h>
#include <hip/hip_bf16.h>
#include <math.h>

// ---------------------------------------------------------------------------
// PairEmbed: pairwise features -> BN0 -> [conv1x1+BN+GELU] x2 -> conv1x1+BN
// -> symmetric scatter to (B,64,N,N).  B=64, N=128, channels 14->64->64->64.
//
// R7 restructure (from rocprof: 315us, VALUBusy 45%, occ 20.5%, HBM 10.8%):
// latency-bound at 1.6 waves/SIMD. Split each pair across 2 threads (OC=32):
// block = 512 thr = one 16x16 tile x 2 o-halves. Same LDS/block (73.75KB)
// but 8 waves/block -> 2 blocks/CU = 16 waves/CU, VGPR ~80 -> 4 waves/SIMD.
// Weight reads stay wave-uniform (q = tid>>8) -> s_load broadcast. Arithmetic
// is bit-identical to the R7 passing kernel (same per-output FMA order).
// ---------------------------------------------------------------------------

#define NTF 256       // fold_kernel threads
#define NTM 512       // pair_kernel threads
#define OC  32        // outputs per thread
#define NTILES 36     // 8*9/2 tril 16x16 tiles

// ws float layout
#define WS_W1T 0      // [14][64]
#define WS_B1  896
#define WS_W2T 960    // [64][64] transposed: [c][o]
#define WS_B2  5056
#define WS_W3T 5120   // [64][64] transposed
#define WS_B3  9216

__device__ __forceinline__ float gelu_exact(float x) {
    // 0.5*x*(1+erf(x/sqrt(2))), erf via Abramowitz-Stegun 7.1.26 (|err|<=1.5e-7)
    float a = fabsf(x) * 0.70710678118654752440f;
    float t = __builtin_amdgcn_rcpf(fmaf(0.3275911f, a, 1.0f));
    float poly = t * fmaf(t, fmaf(t, fmaf(t, fmaf(t, 1.061405429f, -1.453152027f),
                                          1.421413741f), -0.284496736f), 0.254829592f);
    float e = __expf(-a * a);
    float erf_a = fmaf(-poly, e, 1.0f);
    float erfx = copysignf(erf_a, x);
    return 0.5f * x * (1.0f + erfx);
}

// ---------------------------------------------------------------------------
// Setup: fold BN params into conv weights/biases. One block, 256 threads.
// ---------------------------------------------------------------------------
__global__ void fold_kernel(
    const float* __restrict__ bn0g, const float* __restrict__ bn0b,
    const float* __restrict__ bn0m, const float* __restrict__ bn0v,
    const float* __restrict__ bn1g, const float* __restrict__ bn1b,
    const float* __restrict__ bn1m, const float* __restrict__ bn1v,
    const float* __restrict__ bn2g, const float* __restrict__ bn2b,
    const float* __restrict__ bn2m, const float* __restrict__ bn2v,
    const float* __restrict__ bn3g, const float* __restrict__ bn3b,
    const float* __restrict__ bn3m, const float* __restrict__ bn3v,
    const float* __restrict__ w1, const float* __restrict__ b1,
    const float* __restrict__ w2, const float* __restrict__ b2,
    const float* __restrict__ w3, const float* __restrict__ b3,
    float* __restrict__ ws)
{
    __shared__ float s0[14], t0[14];
    __shared__ float s1[64], t1[64], s2[64], t2[64], s3[64], t3[64];
    const int tid = threadIdx.x;
    if (tid < 14) {
        float s = bn0g[tid] / sqrtf(bn0v[tid] + 1e-5f);
        s0[tid] = s; t0[tid] = bn0b[tid] - bn0m[tid] * s;
    } else if (tid < 78) {
        int o = tid - 14;
        float s = bn1g[o] / sqrtf(bn1v[o] + 1e-5f);
        s1[o] = s; t1[o] = bn1b[o] - bn1m[o] * s;
    } else if (tid < 142) {
        int o = tid - 78;
        float s = bn2g[o] / sqrtf(bn2v[o] + 1e-5f);
        s2[o] = s; t2[o] = bn2b[o] - bn2m[o] * s;
    } else if (tid < 206) {
        int o = tid - 142;
        float s = bn3g[o] / sqrtf(bn3v[o] + 1e-5f);
        s3[o] = s; t3[o] = bn3b[o] - bn3m[o] * s;
    }
    __syncthreads();
    // W1T[c*64+o] = w1[o,c] * s0[c] * s1[o]  (BN0 folded input-side, BN1 output-side)
    for (int idx = tid; idx < 896; idx += NTF) {
        int c = idx >> 6, o = idx & 63;
        ws[WS_W1T + idx] = w1[o * 14 + c] * s0[c] * s1[o];
    }
    if (tid < 64) {
        float acc = b1[tid];
        #pragma unroll
        for (int c = 0; c < 14; ++c) acc += w1[tid * 14 + c] * t0[c];
        ws[WS_B1 + tid] = acc * s1[tid] + t1[tid];
        ws[WS_B2 + tid] = b2[tid] * s2[tid] + t2[tid];
        ws[WS_B3 + tid] = b3[tid] * s3[tid] + t3[tid];
    }
    for (int idx = tid; idx < 4096; idx += NTF) {
        int c = idx >> 6, o = idx & 63;
        ws[WS_W2T + idx] = w2[o * 64 + c] * s2[o];
        ws[WS_W3T + idx] = w3[o * 64 + c] * s3[o];
    }
}

// ---------------------------------------------------------------------------
// Main kernel: grid (36, 64) x 512 threads. 2 threads per (i,j) tile cell,
// each owning 32 of the 64 output channels (q = tid>>8, wave-uniform).
// ---------------------------------------------------------------------------
__global__ __launch_bounds__(NTM, 4) void pair_kernel(
    const float* __restrict__ x, const float* __restrict__ z,
    const float* __restrict__ ws, float* __restrict__ out)
{
    // smem: nf (128 nodes x 18 feats = 2304 f) | h (64 ch x 256 pairs = 16384 f)
    // mirror stage reuses smem[0..8704) after h is dead. Total 74752 B.
    __shared__ float smem[2304 + 16384];
    float* nf = smem;
    float* h  = smem + 2304;

    const int tid = threadIdx.x;
    const int b = blockIdx.y;

    // tile decode: blockIdx.x -> (I,J), J<=I, over the 8x8 tile grid
    int I = 0;
    {
        const int t = blockIdx.x;
        while ((I + 1) * (I + 2) / 2 <= t) ++I;
    }
    const int J = blockIdx.x - I * (I + 1) / 2;

    if (tid < 128) {
        const int n = tid;
        const float* xb = x + (size_t)b * 4 * 128 + n;
        float px = xb[0], py = xb[128], pz = xb[256], e = xb[384];
        float pt  = sqrtf(fmaxf(px * px + py * py, 1e-8f));
        float rap = 0.5f * logf(1.0f + 2.0f * pz / fmaxf(e - pz, 1e-20f));
        float phi = atan2f(py, px);
        float* nr = nf + n * 18;
        nr[0] = px; nr[1] = py; nr[2] = pz; nr[3] = e;
        nr[4] = pt; nr[5] = rap; nr[6] = phi;
        const float* zb = z + (size_t)b * 17 * 128 + n;
        #pragma unroll
        for (int q2 = 0; q2 < 6; ++q2) nr[7 + q2] = zb[(5 + q2) * 128];
        nr[13] = zb[11 * 128];  // d0
        nr[14] = zb[13 * 128];  // d1
        nr[15] = zb[12 * 128];  // derr0
        nr[16] = zb[14 * 128];  // derr1
    }
    __syncthreads();

    const int q  = tid >> 8;          // o-half: 0 or 1 (wave-uniform)
    const int p  = tid & 255;         // pair index within tile
    const int ob = q * OC;            // output-channel base
    const int ti = p >> 4;            // tile-local row
    const int tj = p & 15;            // tile-local col
    const int i = I * 16 + ti;
    const int j = J * 16 + tj;

    const float* ni = nf + i * 18;
    const float* nj = nf + j * 18;

    // ---- pairwise features (redundant per o-half; identical results) ----
    float fts[14];
    {
        const float PI = 3.14159265358979323846f;
        float pti = ni[4], rapi = ni[5], phii = ni[6];
        float ptj = nj[4], rapj = nj[5], phij = nj[6];
        float d = phii - phij + PI;
        d -= floorf(d * (0.5f / PI)) * (2.0f * PI);   // jnp.mod semantics
        float dphi = d - PI;
        float drap = rapi - rapj;
        float delta = sqrtf(drap * drap + dphi * dphi);
        fts[0] = logf(fmaxf(delta, 1e-8f));
        float ptmin = fminf(pti, ptj);
        fts[1] = logf(fmaxf(ptmin * delta, 1e-8f));
        fts[2] = logf(fmaxf(ptmin / fmaxf(pti + ptj, 1e-8f), 1e-8f));
        float Px = ni[0] + nj[0], Py = ni[1] + nj[1];
        float Pz = ni[2] + nj[2], E  = ni[3] + nj[3];
        float m2 = fmaxf(E * E - Px * Px - Py * Py - Pz * Pz, 1e-8f);
        fts[3] = logf(m2);
        #pragma unroll
        for (int q2 = 0; q2 < 6; ++q2) fts[4 + q2] = ni[7 + q2] + nj[7 + q2];
        #pragma unroll
        for (int q2 = 0; q2 < 2; ++q2) {
            float di = ni[13 + q2], dj = nj[13 + q2];
            fts[10 + q2] = (di + dj) / fmaf(di, dj, 1.0f + 1e-8f);
            float ei = ni[15 + q2], ej = nj[15 + q2];
            fts[12 + q2] = sqrtf(ei * ei + ej * ej);
        }
    }

    float acc[OC];

    // ---- layer 1: 14 -> 64 (this thread's 32), BN0+BN1 folded ----
    #pragma unroll
    for (int o2 = 0; o2 < OC; ++o2) acc[o2] = ws[WS_B1 + ob + o2];
    #pragma unroll
    for (int c = 0; c < 14; ++c) {
        float f = fts[c];
        #pragma unroll
        for (int o2 = 0; o2 < OC; ++o2)
            acc[o2] = fmaf(ws[WS_W1T + c * 64 + ob + o2], f, acc[o2]);
    }
    #pragma unroll
    for (int o2 = 0; o2 < OC; ++o2) h[(ob + o2) * 256 + p] = gelu_exact(acc[o2]);
    __syncthreads();                      // g1 visible to both o-halves

    // ---- layer 2: 64 -> 64 (this thread's 32) ----
    #pragma unroll
    for (int o2 = 0; o2 < OC; ++o2) acc[o2] = ws[WS_B2 + ob + o2];
    {
        const float* hp = h + p;
        #pragma unroll 4
        for (int c = 0; c < 64; ++c) {    // weights via s_load broadcast
            float f = hp[c * 256];
            #pragma unroll
            for (int o2 = 0; o2 < OC; ++o2)
                acc[o2] = fmaf(ws[WS_W2T + c * 64 + ob + o2], f, acc[o2]);
        }
    }
    __syncthreads();                      // all g1 reads done
    #pragma unroll
    for (int o2 = 0; o2 < OC; ++o2) h[(ob + o2) * 256 + p] = gelu_exact(acc[o2]);
    __syncthreads();                      // g2 visible

    // ---- layer 3: 64 -> 64 (no activation) ----
    #pragma unroll
    for (int o2 = 0; o2 < OC; ++o2) acc[o2] = ws[WS_B3 + ob + o2];
    {
        const float* hp = h + p;
        #pragma unroll 4
        for (int c = 0; c < 64; ++c) {
            float f = hp[c * 256];
            #pragma unroll
            for (int o2 = 0; o2 < OC; ++o2)
                acc[o2] = fmaf(ws[WS_W3T + c * 64 + ob + o2], f, acc[o2]);
        }
    }

    // ---- direct store: y[b,ob+o2,i,j] — 4x64B full-line segments/wave ----
    float* outb = out + (size_t)b * 64 * 16384 + (size_t)i * 128 + j;
    #pragma unroll
    for (int o2 = 0; o2 < OC; ++o2) outb[(size_t)(ob + o2) * 16384] = acc[o2];

    // ---- mirror store: y[b,o,j,i] via LDS transpose (diagonal tiles skip;
    //      their direct store already covered the mirror cells). Stage
    //      overlaps dead nf/h: per (q,chunk) 16x16x17 floats. ----
    if (I != J) {
        float* stage = smem + q * 4352;
        #pragma unroll
        for (int oc = 0; oc < 2; ++oc) {
            __syncthreads();              // h/nf reads (and prev chunk) done
            #pragma unroll
            for (int k = 0; k < 16; ++k)
                stage[(k * 16 + tj) * 17 + ti] = acc[oc * 16 + k];
            __syncthreads();
            float* outm = out + ((size_t)b * 64 + ob + oc * 16) * 16384
                              + (size_t)(J * 16 + ti) * 128 + (I * 16 + tj);
            #pragma unroll
            for (int k = 0; k < 16; ++k)
                outm[(size_t)k * 16384] = stage[(k * 16 + ti) * 17 + tj];
        }
    }
}

extern "C" void kernel_launch(void* const* d_in, const int* in_sizes, int n_in,
                              void* d_out, int out_size, void* d_ws, size_t ws_size,
                              hipStream_t stream) {
    const float* x = (const float*)d_in[0];
    const float* z = (const float*)d_in[1];
    const float* bn0g = (const float*)d_in[2],  *bn0b = (const float*)d_in[3];
    const float* bn0m = (const float*)d_in[4],  *bn0v = (const float*)d_in[5];
    const float* bn1g = (const float*)d_in[6],  *bn1b = (const float*)d_in[7];
    const float* bn1m = (const float*)d_in[8],  *bn1v = (const float*)d_in[9];
    const float* bn2g = (const float*)d_in[10], *bn2b = (const float*)d_in[11];
    const float* bn2m = (const float*)d_in[12], *bn2v = (const float*)d_in[13];
    const float* bn3g = (const float*)d_in[14], *bn3b = (const float*)d_in[15];
    const float* bn3m = (const float*)d_in[16], *bn3v = (const float*)d_in[17];
    const float* w1 = (const float*)d_in[18], *b1 = (const float*)d_in[19];
    const float* w2 = (const float*)d_in[20], *b2 = (const float*)d_in[21];
    const float* w3 = (const float*)d_in[22], *b3 = (const float*)d_in[23];
    float* ws  = (float*)d_ws;
    float* out = (float*)d_out;

    hipLaunchKernelGGL(fold_kernel, dim3(1), dim3(NTF), 0, stream,
                       bn0g, bn0b, bn0m, bn0v, bn1g, bn1b, bn1m, bn1v,
                       bn2g, bn2b, bn2m, bn2v, bn3g, bn3b, bn3m, bn3v,
                       w1, b1, w2, b2, w3, b3, ws);

    hipLaunchKernelGGL(pair_kernel, dim3(NTILES, 64), dim3(NTM), 0, stream,
                       x, z, ws, out);
}

// Round 13
// 444.937 us; speedup vs baseline: 1.9516x; 1.9516x over previous
//
#include <hip/hip_runtime.h>
#include <hip/hip_bf16.h>
#include <math.h>

// ---------------------------------------------------------------------------
// PairEmbed: pairwise features -> BN0 -> [conv1x1+BN+GELU] x2 -> conv1x1+BN
// -> symmetric scatter to (B,64,N,N).  B=64, N=128, channels 14->64->64->64.
//
// R12 post-mortem: 512thr/OC32/shared-h REGRESSED (315->652us; VALU 45->22%,
// occ 20.5->45.7%, total VALU-cycles identical) -> occupancy bought by
// barrier-coupling waves is negative. Revert to R7's barrier-free structure
// (256 thr, one thread = one pair, 64 private accumulators, thread-private
// h columns), and raise occupancy WITHOUT coupling: h stored as packed
// bf16x2 -> LDS/block 74752->41984 B -> 3 blocks/CU (12 waves, +50% vs R7),
// and layer-2/3 ds_read count halves (one b32 = two channels).
// FMA order identical to the R7-passing kernel; only h carries bf16 rounding.
// ---------------------------------------------------------------------------

#define NT 256        // threads per block
#define NTILES 36     // 8*9/2 tril 16x16 tiles

// ws float layout
#define WS_W1T 0      // [14][64]
#define WS_B1  896
#define WS_W2T 960    // [64][64] transposed: [c][o]
#define WS_B2  5056
#define WS_W3T 5120   // [64][64] transposed
#define WS_B3  9216

__device__ __forceinline__ float gelu_exact(float x) {
    // 0.5*x*(1+erf(x/sqrt(2))), erf via Abramowitz-Stegun 7.1.26 (|err|<=1.5e-7)
    float a = fabsf(x) * 0.70710678118654752440f;
    float t = __builtin_amdgcn_rcpf(fmaf(0.3275911f, a, 1.0f));
    float poly = t * fmaf(t, fmaf(t, fmaf(t, fmaf(t, 1.061405429f, -1.453152027f),
                                          1.421413741f), -0.284496736f), 0.254829592f);
    float e = __expf(-a * a);
    float erf_a = fmaf(-poly, e, 1.0f);
    float erfx = copysignf(erf_a, x);
    return 0.5f * x * (1.0f + erfx);
}

// fp32 -> bf16 bits (round-to-nearest-even), returned in low 16 bits
__device__ __forceinline__ uint32_t f2bf(float f) {
    uint32_t u = __float_as_uint(f);
    return (u + 0x7FFFu + ((u >> 16) & 1u)) >> 16;
}

// ---------------------------------------------------------------------------
// Setup: fold BN params into conv weights/biases. One block, 256 threads.
// ---------------------------------------------------------------------------
__global__ void fold_kernel(
    const float* __restrict__ bn0g, const float* __restrict__ bn0b,
    const float* __restrict__ bn0m, const float* __restrict__ bn0v,
    const float* __restrict__ bn1g, const float* __restrict__ bn1b,
    const float* __restrict__ bn1m, const float* __restrict__ bn1v,
    const float* __restrict__ bn2g, const float* __restrict__ bn2b,
    const float* __restrict__ bn2m, const float* __restrict__ bn2v,
    const float* __restrict__ bn3g, const float* __restrict__ bn3b,
    const float* __restrict__ bn3m, const float* __restrict__ bn3v,
    const float* __restrict__ w1, const float* __restrict__ b1,
    const float* __restrict__ w2, const float* __restrict__ b2,
    const float* __restrict__ w3, const float* __restrict__ b3,
    float* __restrict__ ws)
{
    __shared__ float s0[14], t0[14];
    __shared__ float s1[64], t1[64], s2[64], t2[64], s3[64], t3[64];
    const int tid = threadIdx.x;
    if (tid < 14) {
        float s = bn0g[tid] / sqrtf(bn0v[tid] + 1e-5f);
        s0[tid] = s; t0[tid] = bn0b[tid] - bn0m[tid] * s;
    } else if (tid < 78) {
        int o = tid - 14;
        float s = bn1g[o] / sqrtf(bn1v[o] + 1e-5f);
        s1[o] = s; t1[o] = bn1b[o] - bn1m[o] * s;
    } else if (tid < 142) {
        int o = tid - 78;
        float s = bn2g[o] / sqrtf(bn2v[o] + 1e-5f);
        s2[o] = s; t2[o] = bn2b[o] - bn2m[o] * s;
    } else if (tid < 206) {
        int o = tid - 142;
        float s = bn3g[o] / sqrtf(bn3v[o] + 1e-5f);
        s3[o] = s; t3[o] = bn3b[o] - bn3m[o] * s;
    }
    __syncthreads();
    // W1T[c*64+o] = w1[o,c] * s0[c] * s1[o]  (BN0 folded input-side, BN1 output-side)
    for (int idx = tid; idx < 896; idx += NT) {
        int c = idx >> 6, o = idx & 63;
        ws[WS_W1T + idx] = w1[o * 14 + c] * s0[c] * s1[o];
    }
    if (tid < 64) {
        float acc = b1[tid];
        #pragma unroll
        for (int c = 0; c < 14; ++c) acc += w1[tid * 14 + c] * t0[c];
        ws[WS_B1 + tid] = acc * s1[tid] + t1[tid];
        ws[WS_B2 + tid] = b2[tid] * s2[tid] + t2[tid];
        ws[WS_B3 + tid] = b3[tid] * s3[tid] + t3[tid];
    }
    for (int idx = tid; idx < 4096; idx += NT) {
        int c = idx >> 6, o = idx & 63;
        ws[WS_W2T + idx] = w2[o * 64 + c] * s2[o];
        ws[WS_W3T + idx] = w3[o * 64 + c] * s3[o];
    }
}

// ---------------------------------------------------------------------------
// Main kernel: grid (36, 64) x 256 threads. One thread per (i,j) tile cell.
// LDS 41984 B -> 3 blocks/CU, barrier-free layer pipeline.
// ---------------------------------------------------------------------------
__global__ __launch_bounds__(NT) void pair_kernel(
    const float* __restrict__ x, const float* __restrict__ z,
    const float* __restrict__ ws, float* __restrict__ out)
{
    // smem: nf float[128*18] | h2 packed-bf16x2 [32][256]. Mirror stage
    // (4352 floats = 17408 B) overlays the front after nf/h2 are dead.
    __shared__ uint32_t smem[2304 + 8192];
    float* nf = (float*)smem;
    uint32_t* h2 = smem + 2304;

    const int tid = threadIdx.x;
    const int b = blockIdx.y;

    // tile decode: blockIdx.x -> (I,J), J<=I, over the 8x8 tile grid
    int I = 0;
    {
        const int t = blockIdx.x;
        while ((I + 1) * (I + 2) / 2 <= t) ++I;
    }
    const int J = blockIdx.x - I * (I + 1) / 2;

    if (tid < 128) {
        const int n = tid;
        const float* xb = x + (size_t)b * 4 * 128 + n;
        float px = xb[0], py = xb[128], pz = xb[256], e = xb[384];
        float pt  = sqrtf(fmaxf(px * px + py * py, 1e-8f));
        float rap = 0.5f * logf(1.0f + 2.0f * pz / fmaxf(e - pz, 1e-20f));
        float phi = atan2f(py, px);
        float* nr = nf + n * 18;
        nr[0] = px; nr[1] = py; nr[2] = pz; nr[3] = e;
        nr[4] = pt; nr[5] = rap; nr[6] = phi;
        const float* zb = z + (size_t)b * 17 * 128 + n;
        #pragma unroll
        for (int q = 0; q < 6; ++q) nr[7 + q] = zb[(5 + q) * 128];
        nr[13] = zb[11 * 128];  // d0
        nr[14] = zb[13 * 128];  // d1
        nr[15] = zb[12 * 128];  // derr0
        nr[16] = zb[14 * 128];  // derr1
    }
    __syncthreads();

    const int ti = tid >> 4;           // tile-local row
    const int tj = tid & 15;           // tile-local col
    const int i = I * 16 + ti;
    const int j = J * 16 + tj;

    const float* ni = nf + i * 18;
    const float* nj = nf + j * 18;

    // ---- pairwise features (precise logf: feeds the whole network) ----
    float fts[14];
    {
        const float PI = 3.14159265358979323846f;
        float pti = ni[4], rapi = ni[5], phii = ni[6];
        float ptj = nj[4], rapj = nj[5], phij = nj[6];
        float d = phii - phij + PI;
        d -= floorf(d * (0.5f / PI)) * (2.0f * PI);   // jnp.mod semantics
        float dphi = d - PI;
        float drap = rapi - rapj;
        float delta = sqrtf(drap * drap + dphi * dphi);
        fts[0] = logf(fmaxf(delta, 1e-8f));
        float ptmin = fminf(pti, ptj);
        fts[1] = logf(fmaxf(ptmin * delta, 1e-8f));
        fts[2] = logf(fmaxf(ptmin / fmaxf(pti + ptj, 1e-8f), 1e-8f));
        float Px = ni[0] + nj[0], Py = ni[1] + nj[1];
        float Pz = ni[2] + nj[2], E  = ni[3] + nj[3];
        float m2 = fmaxf(E * E - Px * Px - Py * Py - Pz * Pz, 1e-8f);
        fts[3] = logf(m2);
        #pragma unroll
        for (int q = 0; q < 6; ++q) fts[4 + q] = ni[7 + q] + nj[7 + q];
        #pragma unroll
        for (int q = 0; q < 2; ++q) {
            float di = ni[13 + q], dj = nj[13 + q];
            fts[10 + q] = (di + dj) / fmaf(di, dj, 1.0f + 1e-8f);
            float ei = ni[15 + q], ej = nj[15 + q];
            fts[12 + q] = sqrtf(ei * ei + ej * ej);
        }
    }

    float acc[64];

    // ---- layer 1: 14 -> 64 (BN0+BN1 folded), fully unrolled ----
    #pragma unroll
    for (int o = 0; o < 64; ++o) acc[o] = ws[WS_B1 + o];
    #pragma unroll
    for (int c = 0; c < 14; ++c) {
        float f = fts[c];
        #pragma unroll
        for (int o = 0; o < 64; ++o) acc[o] = fmaf(ws[WS_W1T + c * 64 + o], f, acc[o]);
    }
    #pragma unroll
    for (int c2 = 0; c2 < 32; ++c2) {
        float g0 = gelu_exact(acc[2 * c2]);
        float g1 = gelu_exact(acc[2 * c2 + 1]);
        h2[c2 * 256 + tid] = f2bf(g0) | (f2bf(g1) << 16);
    }

    // ---- layer 2: 64 -> 64 (thread-private h columns, no barrier) ----
    #pragma unroll
    for (int o = 0; o < 64; ++o) acc[o] = ws[WS_B2 + o];
    {
        const uint32_t* hp = h2 + tid;
        #pragma unroll 2
        for (int c2 = 0; c2 < 32; ++c2) {       // weights via s_load broadcast
            uint32_t u = hp[c2 * 256];
            float f0 = __uint_as_float(u << 16);
            float f1 = __uint_as_float(u & 0xFFFF0000u);
            #pragma unroll
            for (int o = 0; o < 64; ++o)
                acc[o] = fmaf(ws[WS_W2T + (2 * c2) * 64 + o], f0, acc[o]);
            #pragma unroll
            for (int o = 0; o < 64; ++o)
                acc[o] = fmaf(ws[WS_W2T + (2 * c2 + 1) * 64 + o], f1, acc[o]);
        }
    }
    #pragma unroll
    for (int c2 = 0; c2 < 32; ++c2) {
        float g0 = gelu_exact(acc[2 * c2]);
        float g1 = gelu_exact(acc[2 * c2 + 1]);
        h2[c2 * 256 + tid] = f2bf(g0) | (f2bf(g1) << 16);
    }

    // ---- layer 3: 64 -> 64 (no activation) ----
    #pragma unroll
    for (int o = 0; o < 64; ++o) acc[o] = ws[WS_B3 + o];
    {
        const uint32_t* hp = h2 + tid;
        #pragma unroll 2
        for (int c2 = 0; c2 < 32; ++c2) {
            uint32_t u = hp[c2 * 256];
            float f0 = __uint_as_float(u << 16);
            float f1 = __uint_as_float(u & 0xFFFF0000u);
            #pragma unroll
            for (int o = 0; o < 64; ++o)
                acc[o] = fmaf(ws[WS_W3T + (2 * c2) * 64 + o], f0, acc[o]);
            #pragma unroll
            for (int o = 0; o < 64; ++o)
                acc[o] = fmaf(ws[WS_W3T + (2 * c2 + 1) * 64 + o], f1, acc[o]);
        }
    }

    // ---- direct store: y[b,o,i,j] — 4x64B full-line segments per wave ----
    float* outb = out + (size_t)b * 64 * 16384 + (size_t)i * 128 + j;
    #pragma unroll
    for (int o = 0; o < 64; ++o) outb[(size_t)o * 16384] = acc[o];

    // ---- mirror store: y[b,o,j,i] via LDS transpose (skip diagonal tiles,
    //      their direct store already covered the mirror region) ----
    if (I != J) {
        float* stage = (float*)smem;   // overlays dead nf/h2; barriered below
        #pragma unroll
        for (int oc = 0; oc < 4; ++oc) {
            __syncthreads();
            #pragma unroll
            for (int o2 = 0; o2 < 16; ++o2)
                stage[(o2 * 16 + tj) * 17 + ti] = acc[oc * 16 + o2];
            __syncthreads();
            float* outm = out + ((size_t)b * 64 + oc * 16) * 16384
                              + (size_t)(J * 16 + ti) * 128 + (I * 16 + tj);
            #pragma unroll
            for (int o2 = 0; o2 < 16; ++o2)
                outm[(size_t)o2 * 16384] = stage[(o2 * 16 + ti) * 17 + tj];
        }
    }
}

extern "C" void kernel_launch(void* const* d_in, const int* in_sizes, int n_in,
                              void* d_out, int out_size, void* d_ws, size_t ws_size,
                              hipStream_t stream) {
    const float* x = (const float*)d_in[0];
    const float* z = (const float*)d_in[1];
    const float* bn0g = (const float*)d_in[2],  *bn0b = (const float*)d_in[3];
    const float* bn0m = (const float*)d_in[4],  *bn0v = (const float*)d_in[5];
    const float* bn1g = (const float*)d_in[6],  *bn1b = (const float*)d_in[7];
    const float* bn1m = (const float*)d_in[8],  *bn1v = (const float*)d_in[9];
    const float* bn2g = (const float*)d_in[10], *bn2b = (const float*)d_in[11];
    const float* bn2m = (const float*)d_in[12], *bn2v = (const float*)d_in[13];
    const float* bn3g = (const float*)d_in[14], *bn3b = (const float*)d_in[15];
    const float* bn3m = (const float*)d_in[16], *bn3v = (const float*)d_in[17];
    const float* w1 = (const float*)d_in[18], *b1 = (const float*)d_in[19];
    const float* w2 = (const float*)d_in[20], *b2 = (const float*)d_in[21];
    const float* w3 = (const float*)d_in[22], *b3 = (const float*)d_in[23];
    float* ws  = (float*)d_ws;
    float* out = (float*)d_out;

    hipLaunchKernelGGL(fold_kernel, dim3(1), dim3(NT), 0, stream,
                       bn0g, bn0b, bn0m, bn0v, bn1g, bn1b, bn1m, bn1v,
                       bn2g, bn2b, bn2m, bn2v, bn3g, bn3b, bn3m, bn3v,
                       w1, b1, w2, b2, w3, b3, ws);

    hipLaunchKernelGGL(pair_kernel, dim3(NTILES, 64), dim3(NT), 0, stream,
                       x, z, ws, out);
}